// Round 1
// baseline (329.586 us; speedup 1.0000x reference)
//
#include <hip/hip_runtime.h>

// conv2d NCHW/OIHW, stride 1, VALID. x=(64,3,256,256) f32, w=(16,3,3,3), b=(16)
// out=(64,16,254,254) f32.
// Traffic floor: 264 MB write + 50 MB read ≈ 50 us at 6.3 TB/s.
//
// R1 restructure: the previous version fetched weights 432x per thread in the
// innermost loop with 32 live accumulators -> just-in-time weight loads with
// no latency-hiding window (latency-bound at ~15% HBM BW). Now:
//   - 3x3x4 input patch preloaded ONCE into 36 VGPRs (aligned float2 pairs,
//     ow even -> 8B aligned; rows are 1 KB apart so each row read coalesces).
//   - oc is the OUTER loop: 27 weights per oc are CONTIGUOUS -> merged wide
//     s_load (uniform address, const __restrict__ -> SMEM-selectable), with
//     54 FMAs per oc as the latency-hiding window.
//   - store each oc's float2 inside the loop -> only 2 live accumulators;
//     VGPR ~55 -> ~8 waves/SIMD for TLP latency hiding.
// Math order per output is unchanged (c, kh, kw ascending) -> same absmax.

constexpr int N = 64, C = 3, H = 256, W = 256;
constexpr int OC = 16, K = 3, OH = 254, OW = 254;
constexpr int PW = OW / 2;  // 127 pixel-pairs per output row

__global__ __launch_bounds__(256) void conv3x3_kernel(
    const float* __restrict__ x, const float* __restrict__ w,
    const float* __restrict__ bias, float* __restrict__ out)
{
    int idx = blockIdx.x * blockDim.x + threadIdx.x;
    constexpr int total = N * OH * PW;
    if (idx >= total) return;

    int pw = idx % PW;          // which pixel pair in the row
    int t  = idx / PW;
    int oh = t % OH;
    int n  = t / OH;
    int ow = pw * 2;

    const float* xb = x + (size_t)n * C * H * W;

    // Preload the full input patch: C*K rows x 4 columns = 36 VGPRs.
    float xin[C][K][4];
    #pragma unroll
    for (int c = 0; c < C; ++c) {
        #pragma unroll
        for (int kh = 0; kh < K; ++kh) {
            const float* xr = xb + ((size_t)c * H + (oh + kh)) * W + ow;
            float2 lo = *reinterpret_cast<const float2*>(xr);      // 8B aligned
            float2 hi = *reinterpret_cast<const float2*>(xr + 2);
            xin[c][kh][0] = lo.x;
            xin[c][kh][1] = lo.y;
            xin[c][kh][2] = hi.x;
            xin[c][kh][3] = hi.y;
        }
    }

    // oc outermost: 27 contiguous weights per iteration -> wide scalar loads,
    // 54 FMAs of hiding window, only 2 live accumulators.
    #pragma unroll
    for (int oc = 0; oc < OC; ++oc) {
        const float* wp = w + oc * (C * K * K);
        float b  = bias[oc];    // uniform -> scalar load
        float a0 = b, a1 = b;
        #pragma unroll
        for (int c = 0; c < C; ++c) {
            #pragma unroll
            for (int kh = 0; kh < K; ++kh) {
                float w0 = wp[(c * K + kh) * K + 0];
                float w1 = wp[(c * K + kh) * K + 1];
                float w2 = wp[(c * K + kh) * K + 2];
                a0 += xin[c][kh][0] * w0 + xin[c][kh][1] * w1 + xin[c][kh][2] * w2;
                a1 += xin[c][kh][1] * w0 + xin[c][kh][2] * w1 + xin[c][kh][3] * w2;
            }
        }
        float* ob = out + (((size_t)n * OC + oc) * OH + oh) * OW + ow;
        *reinterpret_cast<float2*>(ob) = make_float2(a0, a1);  // 8B aligned
    }
}

extern "C" void kernel_launch(void* const* d_in, const int* in_sizes, int n_in,
                              void* d_out, int out_size, void* d_ws, size_t ws_size,
                              hipStream_t stream) {
    const float* x    = (const float*)d_in[0];
    const float* w    = (const float*)d_in[1];
    const float* bias = (const float*)d_in[2];
    float* out        = (float*)d_out;

    constexpr int total  = N * OH * PW;
    constexpr int block  = 256;
    constexpr int blocks = (total + block - 1) / block;
    conv3x3_kernel<<<blocks, block, 0, stream>>>(x, w, bias, out);
}

// Round 3
// 314.198 us; speedup vs baseline: 1.0490x; 1.0490x over previous
//
#include <hip/hip_runtime.h>

// conv2d NCHW/OIHW, stride 1, VALID. x=(64,3,256,256) f32, w=(16,3,3,3), b=(16)
// out=(64,16,254,254) f32.
// Traffic floor: 264 MB write + 50 MB read ≈ 50 us at 6.3 TB/s.
//
// R3 = R2 with the compile fix: __builtin_nontemporal_store requires NATIVE
// clang vector types (ext_vector_type), not HIP_vector_type float4/float2.
//
// R2 rationale: 4 pixels per thread (was 2). R0 (weights innermost, 32 acc)
// and R1 (oc outer, 2 acc) timed IDENTICAL (~157 us conv) -> not bound by
// register schedule; memory-instruction path is the suspect. This version:
//   - input: per (c,kh) one aligned float4 + one float2 -> 6 cols / 4 pixels
//     (1.5 cols/pixel vs 2.0; half the load instrs per pixel)
//   - stores: aligned 16B NONTEMPORAL (full-line 1KB/wave-instr, no L2
//     pollution from the 264 MB streaming output), half the store instrs/byte
//   - weights: 27 contiguous s_load floats per oc, amortized over 4 pixels
//   - tail: OW=254 = 63*4+2; chunk 63 clamps its 2nd load in-row (never OOB)
//     and stores 8B (1 diverging lane per wave).
// Math order per pixel unchanged (c, kh ascending, kw fma-chain) -> same absmax.

constexpr int N = 64, C = 3, H = 256, W = 256;
constexpr int OC = 16, K = 3, OH = 254, OW = 254;
constexpr int PW4 = 64;   // 63 full 4-wide chunks + 1 tail (2-wide) per row

typedef float vfloat4 __attribute__((ext_vector_type(4)));
typedef float vfloat2 __attribute__((ext_vector_type(2)));

__global__ __launch_bounds__(256) void conv3x3_kernel(
    const float* __restrict__ x, const float* __restrict__ w,
    const float* __restrict__ bias, float* __restrict__ out)
{
    int idx = blockIdx.x * blockDim.x + threadIdx.x;
    constexpr int total = N * OH * PW4;
    if (idx >= total) return;

    int chunk = idx & (PW4 - 1);    // 0..63 within a wave -> lane==chunk
    int t  = idx >> 6;
    int oh = t % OH;
    int n  = t / OH;
    int ow = chunk * 4;
    bool tail = (chunk == PW4 - 1); // ow=252: only 2 valid pixels

    const float* xb = x + (size_t)n * C * H * W;

    // Input patch: C*K rows x 6 cols = 54 VGPRs. 16B-aligned (ow%4==0).
    // Tail clamps hi-load to cols 254..255 (in-row, values unused).
    float xin[C][K][6];
    #pragma unroll
    for (int c = 0; c < C; ++c) {
        #pragma unroll
        for (int kh = 0; kh < K; ++kh) {
            const float* xr = xb + ((size_t)c * H + (oh + kh)) * W + ow;
            vfloat4 lo = *reinterpret_cast<const vfloat4*>(xr);
            const float* xr2 = xr + (tail ? 2 : 4);
            vfloat2 hi = *reinterpret_cast<const vfloat2*>(xr2);
            xin[c][kh][0] = lo.x; xin[c][kh][1] = lo.y;
            xin[c][kh][2] = lo.z; xin[c][kh][3] = lo.w;
            xin[c][kh][4] = hi.x; xin[c][kh][5] = hi.y;
        }
    }

    #pragma unroll
    for (int oc = 0; oc < OC; ++oc) {
        const float* wp = w + oc * (C * K * K);
        float b  = bias[oc];        // uniform -> scalar load
        float a0 = b, a1 = b, a2 = b, a3 = b;
        #pragma unroll
        for (int c = 0; c < C; ++c) {
            #pragma unroll
            for (int kh = 0; kh < K; ++kh) {
                float w0 = wp[(c * K + kh) * K + 0];
                float w1 = wp[(c * K + kh) * K + 1];
                float w2 = wp[(c * K + kh) * K + 2];
                a0 += xin[c][kh][0] * w0 + xin[c][kh][1] * w1 + xin[c][kh][2] * w2;
                a1 += xin[c][kh][1] * w0 + xin[c][kh][2] * w1 + xin[c][kh][3] * w2;
                a2 += xin[c][kh][2] * w0 + xin[c][kh][3] * w1 + xin[c][kh][4] * w2;
                a3 += xin[c][kh][3] * w0 + xin[c][kh][4] * w1 + xin[c][kh][5] * w2;
            }
        }
        float* ob = out + (((size_t)n * OC + oc) * OH + oh) * OW + ow;
        if (!tail) {
            vfloat4 v4 = {a0, a1, a2, a3};
            __builtin_nontemporal_store(v4, reinterpret_cast<vfloat4*>(ob));
        } else {
            vfloat2 v2 = {a0, a1};
            __builtin_nontemporal_store(v2, reinterpret_cast<vfloat2*>(ob));
        }
    }
}

extern "C" void kernel_launch(void* const* d_in, const int* in_sizes, int n_in,
                              void* d_out, int out_size, void* d_ws, size_t ws_size,
                              hipStream_t stream) {
    const float* x    = (const float*)d_in[0];
    const float* w    = (const float*)d_in[1];
    const float* bias = (const float*)d_in[2];
    float* out        = (float*)d_out;

    constexpr int total  = N * OH * PW4;   // 64*254*64 = 1,040,384
    constexpr int block  = 256;
    constexpr int blocks = (total + block - 1) / block;  // 4064
    conv3x3_kernel<<<blocks, block, 0, stream>>>(x, w, bias, out);
}